// Round 13
// baseline (1995.712 us; speedup 1.0000x reference)
//
#include <hip/hip_runtime.h>
#include <hip/hip_bf16.h>

#define HID 128
#define NEG 0.2f
#define LN_EPS 1e-5f
#define NG 16

static __device__ __forceinline__ float leaky(float x) { return x > 0.f ? x : NEG * x; }

static __device__ __forceinline__ unsigned pack_bf2(float a, float b) {
  __hip_bfloat16 ha = __float2bfloat16(a), hb = __float2bfloat16(b);
  unsigned ua = *reinterpret_cast<unsigned short*>(&ha);
  unsigned ub = *reinterpret_cast<unsigned short*>(&hb);
  return ua | (ub << 16);
}

// ---------------- CSR scan ----------------
__global__ __launch_bounds__(1024) void k_scan_a(const int* __restrict__ deg, int* __restrict__ offs,
                                                 int* __restrict__ part, int N) {
  __shared__ int s[1024];
  int i = blockIdx.x * 1024 + threadIdx.x;
  int v = (i < N) ? deg[i] : 0;
  s[threadIdx.x] = v;
  __syncthreads();
  for (int d = 1; d < 1024; d <<= 1) {
    int t = (threadIdx.x >= d) ? s[threadIdx.x - d] : 0;
    __syncthreads();
    s[threadIdx.x] += t;
    __syncthreads();
  }
  if (i < N) offs[i + 1] = s[threadIdx.x];
  if (threadIdx.x == 1023) part[blockIdx.x] = s[1023];
}

__global__ __launch_bounds__(1024) void k_scan_b(int* __restrict__ part, int nb) {
  __shared__ int s[1024];
  int v = (threadIdx.x < nb) ? part[threadIdx.x] : 0;
  s[threadIdx.x] = v;
  __syncthreads();
  for (int d = 1; d < 1024; d <<= 1) {
    int t = (threadIdx.x >= d) ? s[threadIdx.x - d] : 0;
    __syncthreads();
    s[threadIdx.x] += t;
    __syncthreads();
  }
  if (threadIdx.x < nb) part[threadIdx.x] = (threadIdx.x == 0) ? 0 : s[threadIdx.x - 1];
}

// finalize offs and seed cursor with absolute positions (cursor[i] = offs[i])
__global__ __launch_bounds__(256) void k_scan_c(int* __restrict__ offs, const int* __restrict__ part,
                                                int* __restrict__ cur, int N) {
  int i = blockIdx.x * blockDim.x + threadIdx.x;
  if (i < N) {
    int v = offs[i + 1] + part[i >> 10];
    offs[i + 1] = v;
    if (i + 1 < N) cur[i + 1] = v;
  }
  if (i == 0) { offs[0] = 0; cur[0] = 0; }
}

__global__ __launch_bounds__(256) void k_edge_fill(const int* __restrict__ ei, int E,
                                                   int* __restrict__ cur, int* __restrict__ csr) {
  for (int e = blockIdx.x * blockDim.x + threadIdx.x; e < E; e += gridDim.x * blockDim.x) {
    int d = ei[E + e];
    int slot = atomicAdd(&cur[d], 1);
    csr[slot] = ei[e];
  }
}

// ---------------- fused: tiled GEMM (blocks < ggrid) + edge_count (blocks >= ggrid) ----------------
// gemm: 512 thr = 8 waves; wave rq owns rows rq*4..rq*4+3 of a 32-row tile; lane pr -> cols 2pr,2pr+1
__global__ __launch_bounds__(512) void k_gemm_ec(const float* __restrict__ xin, int xstride,
                                                 const float* __restrict__ W,
                                                 const float* __restrict__ a_s, const float* __restrict__ a_d,
                                                 unsigned* __restrict__ hbf, float* __restrict__ as_out,
                                                 float* __restrict__ ad_out, int N, int ntiles, int ggrid,
                                                 const int* __restrict__ ei, int E, int* __restrict__ deg) {
  __shared__ float Ws[HID * HID];   // 64 KB
  __shared__ float xs[32][HID];     // 16 KB -> 80 KB, 2 blocks/CU
  if (blockIdx.x >= ggrid) {
    // edge-count role (independent of gemm inputs)
    if (ei) {
      int nb = gridDim.x - ggrid;
      for (int e = (blockIdx.x - ggrid) * 512 + threadIdx.x; e < E; e += nb * 512)
        atomicAdd(&deg[ei[E + e]], 1);
    }
    return;
  }
  int t = threadIdx.x;
  for (int i = t * 4; i < HID * HID; i += 2048) *(float4*)&Ws[i] = *(const float4*)&W[i];
  int rq = t >> 6, pr = t & 63;
  int c2 = pr * 2;
  float a_s0 = a_s[c2], a_s1 = a_s[c2 + 1], a_d0 = a_d[c2], a_d1 = a_d[c2 + 1];
  for (int tile = blockIdx.x; tile < ntiles; tile += ggrid) {
    int r0 = tile * 32;
    __syncthreads();
#pragma unroll
    for (int i = 0; i < 2; ++i) {
      int idx = i * 512 + t;
      int r = idx >> 5, q = idx & 31;
      float4 v = make_float4(0.f, 0.f, 0.f, 0.f);
      if (r0 + r < N) v = *(const float4*)&xin[(size_t)(r0 + r) * xstride + q * 4];
      *(float4*)&xs[r][q * 4] = v;
    }
    __syncthreads();
    float acc[4][2];
#pragma unroll
    for (int r = 0; r < 4; ++r) { acc[r][0] = 0.f; acc[r][1] = 0.f; }
    for (int k0 = 0; k0 < HID; k0 += 4) {
      float2 w0 = *(const float2*)&Ws[(k0 + 0) * HID + c2];
      float2 w1 = *(const float2*)&Ws[(k0 + 1) * HID + c2];
      float2 w2 = *(const float2*)&Ws[(k0 + 2) * HID + c2];
      float2 w3 = *(const float2*)&Ws[(k0 + 3) * HID + c2];
#pragma unroll
      for (int r = 0; r < 4; ++r) {
        float4 xv = *(const float4*)&xs[rq * 4 + r][k0];
        acc[r][0] = fmaf(xv.x, w0.x, acc[r][0]);
        acc[r][1] = fmaf(xv.x, w0.y, acc[r][1]);
        acc[r][0] = fmaf(xv.y, w1.x, acc[r][0]);
        acc[r][1] = fmaf(xv.y, w1.y, acc[r][1]);
        acc[r][0] = fmaf(xv.z, w2.x, acc[r][0]);
        acc[r][1] = fmaf(xv.z, w2.y, acc[r][1]);
        acc[r][0] = fmaf(xv.w, w3.x, acc[r][0]);
        acc[r][1] = fmaf(xv.w, w3.y, acc[r][1]);
      }
    }
#pragma unroll
    for (int r = 0; r < 4; ++r) {
      int row = r0 + rq * 4 + r;
      float ps = acc[r][0] * a_s0 + acc[r][1] * a_s1;
      float pd = acc[r][0] * a_d0 + acc[r][1] * a_d1;
#pragma unroll
      for (int msk = 1; msk < 16; msk <<= 1) {
        ps += __shfl_xor(ps, msk);
        pd += __shfl_xor(pd, msk);
      }
      if (row < N) {
        hbf[(size_t)row * 64 + pr] = pack_bf2(acc[r][0], acc[r][1]);
        if ((pr & 15) == 0) {
          as_out[row * 4 + (pr >> 4)] = ps;
          ad_out[row * 4 + (pr >> 4)] = pd;
        }
      }
    }
  }
}

// ---------------- per-dst softmax+agg+LN+ELU (r8 structure, best measured) ----------------
// optional fused per-graph sum: if gsum != nullptr, g==0 lanes atomicAdd y into gsum/gcnt.
__global__ __launch_bounds__(256) void k_gat_agg(const int* __restrict__ offs, const int* __restrict__ csr,
                                                 const float* __restrict__ as, const float* __restrict__ ad,
                                                 const uint4* __restrict__ hb, const float* __restrict__ bias,
                                                 const float* __restrict__ gam, const float* __restrict__ bet,
                                                 float* __restrict__ out, int ostride,
                                                 const int* __restrict__ bat, float* __restrict__ gsum,
                                                 float* __restrict__ gcnt, int N) {
  int wave = threadIdx.x >> 6, lane = threadIdx.x & 63;
  int dst = blockIdx.x * 4 + wave;
  if (dst >= N) return;
  int q = lane & 15, g = lane >> 4, head = q >> 2;
  float ad_h = ad[dst * 4 + head];
  float p_self = __expf(leaky(as[dst * 4 + head] + ad_h));
  float acc[8];
#pragma unroll
  for (int k = 0; k < 8; ++k) acc[k] = 0.f;
  float ssum = 0.f;
  int beg = offs[dst], end = offs[dst + 1];
  for (int base = beg; base < end; base += 64) {
    int idx = base + lane;
    int my = (idx < end) ? csr[idx] : 0;
    int cnt = min(64, end - base);
    int njj = (cnt + 3) >> 2;
    int s0 = __shfl(my, g);
    bool v0 = g < cnt;
    int ss0 = v0 ? s0 : 0;
    float asv0 = as[ss0 * 4 + head];
    uint4 h0 = hb[(size_t)ss0 * 16 + q];
    for (int j = 0; j < njj; ++j) {
      int sel1 = (j + 1) * 4 + g;
      int s1 = __shfl(my, sel1 & 63);
      bool v1 = sel1 < cnt;
      int ss1 = v1 ? s1 : 0;
      float asv1 = as[ss1 * 4 + head];
      uint4 h1 = hb[(size_t)ss1 * 16 + q];
      float p = v0 ? __expf(leaky(asv0 + ad_h)) : 0.f;
      ssum += p;
#pragma unroll
      for (int k = 0; k < 4; ++k) {
        unsigned u = (&h0.x)[k];
        acc[2 * k]     = fmaf(p, __uint_as_float(u << 16), acc[2 * k]);
        acc[2 * k + 1] = fmaf(p, __uint_as_float(u & 0xffff0000u), acc[2 * k + 1]);
      }
      v0 = v1; asv0 = asv1; h0 = h1;
    }
  }
#pragma unroll
  for (int k = 0; k < 8; ++k) {
    acc[k] += __shfl_xor(acc[k], 16);
    acc[k] += __shfl_xor(acc[k], 32);
  }
  float red = ssum;
  red += __shfl_xor(red, 1);
  red += __shfl_xor(red, 2);
  red += __shfl_xor(red, 16);
  red += __shfl_xor(red, 32);
  float denom = 0.25f * red + p_self;
  uint4 hd = hb[(size_t)dst * 16 + q];
#pragma unroll
  for (int k = 0; k < 4; ++k) {
    unsigned u = (&hd.x)[k];
    acc[2 * k]     = fmaf(p_self, __uint_as_float(u << 16), acc[2 * k]);
    acc[2 * k + 1] = fmaf(p_self, __uint_as_float(u & 0xffff0000u), acc[2 * k + 1]);
  }
  int cb = q * 8;
  float inv = 1.f / denom;
  float val[8], part = 0.f;
#pragma unroll
  for (int k = 0; k < 8; ++k) {
    val[k] = acc[k] * inv + bias[cb + k];
    part += val[k];
  }
  part += __shfl_xor(part, 1);
  part += __shfl_xor(part, 2);
  part += __shfl_xor(part, 4);
  part += __shfl_xor(part, 8);
  float mu = part * (1.f / HID);
  float vpart = 0.f;
#pragma unroll
  for (int k = 0; k < 8; ++k) {
    val[k] -= mu;
    vpart += val[k] * val[k];
  }
  vpart += __shfl_xor(vpart, 1);
  vpart += __shfl_xor(vpart, 2);
  vpart += __shfl_xor(vpart, 4);
  vpart += __shfl_xor(vpart, 8);
  float rstd = rsqrtf(vpart * (1.f / HID) + LN_EPS);
  float y[8];
#pragma unroll
  for (int k = 0; k < 8; ++k) {
    float tv = val[k] * rstd * gam[cb + k] + bet[cb + k];
    y[k] = tv > 0.f ? tv : expm1f(tv);
  }
  if (g == 0) {
    *(float4*)&out[(size_t)dst * ostride + cb]     = make_float4(y[0], y[1], y[2], y[3]);
    *(float4*)&out[(size_t)dst * ostride + cb + 4] = make_float4(y[4], y[5], y[6], y[7]);
    if (gsum) {
      int b = bat[dst];
#pragma unroll
      for (int k = 0; k < 8; ++k) atomicAdd(&gsum[b * HID + cb + k], y[k]);
      if (q == 0) atomicAdd(&gcnt[b], 1.f);
    }
  }
}

// g-half of output
__global__ __launch_bounds__(256) void k_gout(const int* __restrict__ bat, const float* __restrict__ gsum,
                                              const float* __restrict__ gcnt, float* __restrict__ out, int N) {
  int total = N * 32;
  for (int idx = blockIdx.x * blockDim.x + threadIdx.x; idx < total; idx += gridDim.x * blockDim.x) {
    int n = idx >> 5, qq = idx & 31;
    int b = bat[n];
    float rin = 1.f / fmaxf(gcnt[b], 1.f);
    float4 gv = *(const float4*)&gsum[b * HID + qq * 4];
    *(float4*)&out[(size_t)n * 256 + 128 + qq * 4] =
        make_float4(gv.x * rin, gv.y * rin, gv.z * rin, gv.w * rin);
  }
}

extern "C" void kernel_launch(void* const* d_in, const int* in_sizes, int n_in,
                              void* d_out, int out_size, void* d_ws, size_t ws_size,
                              hipStream_t stream) {
  const float* x   = (const float*)d_in[0];
  const int*   ei  = (const int*)d_in[1];
  const int*   bat = (const int*)d_in[2];
  const float* W1  = (const float*)d_in[3];
  const float* as1 = (const float*)d_in[4];
  const float* ad1 = (const float*)d_in[5];
  const float* b1  = (const float*)d_in[6];
  const float* g1  = (const float*)d_in[7];
  const float* be1 = (const float*)d_in[8];
  const float* W2  = (const float*)d_in[9];
  const float* as2 = (const float*)d_in[10];
  const float* ad2 = (const float*)d_in[11];
  const float* b2  = (const float*)d_in[12];
  const float* g2  = (const float*)d_in[13];
  const float* be2 = (const float*)d_in[14];
  int N = in_sizes[0] / HID;
  int E = in_sizes[1] / 2;

  char* p = (char*)d_ws;
  auto alloc = [&](size_t bytes) {
    void* r = (void*)p;
    p += (bytes + 255) & ~(size_t)255;
    return r;
  };
  int*      deg  = (int*)alloc((size_t)N * 4);   // counting, then reused as absolute cursor
  int*      offs = (int*)alloc((size_t)(N + 1) * 4);
  int       nsb  = (N + 1023) / 1024;
  int*      part = (int*)alloc((size_t)nsb * 4);
  int*      csr  = (int*)alloc((size_t)E * 4);
  unsigned* hbf  = (unsigned*)alloc((size_t)N * 64 * 4);   // bf16x2-packed h
  float*    asb  = (float*)alloc((size_t)N * 4 * 4);
  float*    adb  = (float*)alloc((size_t)N * 4 * 4);
  float*    xb   = (float*)alloc((size_t)N * HID * 4);
  float*    gsum = (float*)alloc((size_t)NG * HID * 4);
  float*    gcnt = (float*)alloc((size_t)NG * 4);

  hipMemsetAsync(deg, 0, (size_t)N * 4, stream);
  hipMemsetAsync(gsum, 0, (size_t)NG * HID * 4, stream);
  hipMemsetAsync(gcnt, 0, (size_t)NG * 4, stream);

  int ntiles = (N + 31) / 32;
  int ggrid = ntiles < 512 ? ntiles : 512;
  int ecgrid = 512;  // edge-count role blocks
  int agrid = (N + 3) / 4;
  float* xhalf = (float*)d_out;

  // fused: gemm layer 1 + edge_count (independent work, one dispatch)
  k_gemm_ec<<<ggrid + ecgrid, 512, 0, stream>>>(x, HID, W1, as1, ad1, hbf, asb, adb,
                                                N, ntiles, ggrid, ei, E, deg);
  k_scan_a<<<nsb, 1024, 0, stream>>>(deg, offs, part, N);
  k_scan_b<<<1, 1024, 0, stream>>>(part, nsb);
  k_scan_c<<<(N + 255) / 256, 256, 0, stream>>>(offs, part, deg, N);  // deg becomes cursor
  int fgrid = (E + 255) / 256;
  if (fgrid > 2048) fgrid = 2048;
  k_edge_fill<<<fgrid, 256, 0, stream>>>(ei, E, deg, csr);

  k_gat_agg<<<agrid, 256, 0, stream>>>(offs, csr, asb, adb, (const uint4*)hbf, b1, g1, be1,
                                       xb, HID, nullptr, nullptr, nullptr, N);
  // layer-2 gemm (no fused edge-count; pass ei=nullptr so extra blocks exit)
  k_gemm_ec<<<ggrid, 512, 0, stream>>>(xb, HID, W2, as2, ad2, hbf, asb, adb,
                                       N, ntiles, ggrid, nullptr, 0, nullptr);
  // layer-2 agg writes d_out x-half and fuses the per-graph sum
  k_gat_agg<<<agrid, 256, 0, stream>>>(offs, csr, asb, adb, (const uint4*)hbf, b2, g2, be2,
                                       xhalf, 256, bat, gsum, gcnt, N);

  int ogrid = (N * 32 + 255) / 256;
  if (ogrid > 4096) ogrid = 4096;
  k_gout<<<ogrid, 256, 0, stream>>>(bat, gsum, gcnt, (float*)d_out, N);
}

// Round 14
// 569.344 us; speedup vs baseline: 3.5053x; 3.5053x over previous
//
#include <hip/hip_runtime.h>
#include <hip/hip_bf16.h>

#define HID 128
#define NEG 0.2f
#define LN_EPS 1e-5f
#define NG 16

static __device__ __forceinline__ float leaky(float x) { return x > 0.f ? x : NEG * x; }

static __device__ __forceinline__ unsigned pack_bf2(float a, float b) {
  __hip_bfloat16 ha = __float2bfloat16(a), hb = __float2bfloat16(b);
  unsigned ua = *reinterpret_cast<unsigned short*>(&ha);
  unsigned ub = *reinterpret_cast<unsigned short*>(&hb);
  return ua | (ub << 16);
}

// ---------------- CSR scan ----------------
__global__ __launch_bounds__(1024) void k_scan_a(const int* __restrict__ deg, int* __restrict__ offs,
                                                 int* __restrict__ part, int N) {
  __shared__ int s[1024];
  int i = blockIdx.x * 1024 + threadIdx.x;
  int v = (i < N) ? deg[i] : 0;
  s[threadIdx.x] = v;
  __syncthreads();
  for (int d = 1; d < 1024; d <<= 1) {
    int t = (threadIdx.x >= d) ? s[threadIdx.x - d] : 0;
    __syncthreads();
    s[threadIdx.x] += t;
    __syncthreads();
  }
  if (i < N) offs[i + 1] = s[threadIdx.x];
  if (threadIdx.x == 1023) part[blockIdx.x] = s[1023];
}

__global__ __launch_bounds__(1024) void k_scan_b(int* __restrict__ part, int nb) {
  __shared__ int s[1024];
  int v = (threadIdx.x < nb) ? part[threadIdx.x] : 0;
  s[threadIdx.x] = v;
  __syncthreads();
  for (int d = 1; d < 1024; d <<= 1) {
    int t = (threadIdx.x >= d) ? s[threadIdx.x - d] : 0;
    __syncthreads();
    s[threadIdx.x] += t;
    __syncthreads();
  }
  if (threadIdx.x < nb) part[threadIdx.x] = (threadIdx.x == 0) ? 0 : s[threadIdx.x - 1];
}

// finalize offs and seed cursor with absolute positions (cursor[i] = offs[i])
__global__ __launch_bounds__(256) void k_scan_c(int* __restrict__ offs, const int* __restrict__ part,
                                                int* __restrict__ cur, int N) {
  int i = blockIdx.x * blockDim.x + threadIdx.x;
  if (i < N) {
    int v = offs[i + 1] + part[i >> 10];
    offs[i + 1] = v;
    if (i + 1 < N) cur[i + 1] = v;
  }
  if (i == 0) { offs[0] = 0; cur[0] = 0; }
}

__global__ __launch_bounds__(256) void k_edge_fill(const int* __restrict__ ei, int E,
                                                   int* __restrict__ cur, int* __restrict__ csr) {
  for (int e = blockIdx.x * blockDim.x + threadIdx.x; e < E; e += gridDim.x * blockDim.x) {
    int d = ei[E + e];
    int slot = atomicAdd(&cur[d], 1);
    csr[slot] = ei[e];
  }
}

// ---------------- fused: tiled GEMM (blocks < ggrid) + edge_count (blocks >= ggrid) ----------------
__global__ __launch_bounds__(512) void k_gemm_ec(const float* __restrict__ xin, int xstride,
                                                 const float* __restrict__ W,
                                                 const float* __restrict__ a_s, const float* __restrict__ a_d,
                                                 unsigned* __restrict__ hbf, float* __restrict__ as_out,
                                                 float* __restrict__ ad_out, int N, int ntiles, int ggrid,
                                                 const int* __restrict__ ei, int E, int* __restrict__ deg) {
  __shared__ float Ws[HID * HID];   // 64 KB
  __shared__ float xs[32][HID];     // 16 KB -> 80 KB, 2 blocks/CU
  if (blockIdx.x >= ggrid) {
    if (ei) {
      int nb = gridDim.x - ggrid;
      for (int e = (blockIdx.x - ggrid) * 512 + threadIdx.x; e < E; e += nb * 512)
        atomicAdd(&deg[ei[E + e]], 1);
    }
    return;
  }
  int t = threadIdx.x;
  for (int i = t * 4; i < HID * HID; i += 2048) *(float4*)&Ws[i] = *(const float4*)&W[i];
  int rq = t >> 6, pr = t & 63;
  int c2 = pr * 2;
  float a_s0 = a_s[c2], a_s1 = a_s[c2 + 1], a_d0 = a_d[c2], a_d1 = a_d[c2 + 1];
  for (int tile = blockIdx.x; tile < ntiles; tile += ggrid) {
    int r0 = tile * 32;
    __syncthreads();
#pragma unroll
    for (int i = 0; i < 2; ++i) {
      int idx = i * 512 + t;
      int r = idx >> 5, q = idx & 31;
      float4 v = make_float4(0.f, 0.f, 0.f, 0.f);
      if (r0 + r < N) v = *(const float4*)&xin[(size_t)(r0 + r) * xstride + q * 4];
      *(float4*)&xs[r][q * 4] = v;
    }
    __syncthreads();
    float acc[4][2];
#pragma unroll
    for (int r = 0; r < 4; ++r) { acc[r][0] = 0.f; acc[r][1] = 0.f; }
    for (int k0 = 0; k0 < HID; k0 += 4) {
      float2 w0 = *(const float2*)&Ws[(k0 + 0) * HID + c2];
      float2 w1 = *(const float2*)&Ws[(k0 + 1) * HID + c2];
      float2 w2 = *(const float2*)&Ws[(k0 + 2) * HID + c2];
      float2 w3 = *(const float2*)&Ws[(k0 + 3) * HID + c2];
#pragma unroll
      for (int r = 0; r < 4; ++r) {
        float4 xv = *(const float4*)&xs[rq * 4 + r][k0];
        acc[r][0] = fmaf(xv.x, w0.x, acc[r][0]);
        acc[r][1] = fmaf(xv.x, w0.y, acc[r][1]);
        acc[r][0] = fmaf(xv.y, w1.x, acc[r][0]);
        acc[r][1] = fmaf(xv.y, w1.y, acc[r][1]);
        acc[r][0] = fmaf(xv.z, w2.x, acc[r][0]);
        acc[r][1] = fmaf(xv.z, w2.y, acc[r][1]);
        acc[r][0] = fmaf(xv.w, w3.x, acc[r][0]);
        acc[r][1] = fmaf(xv.w, w3.y, acc[r][1]);
      }
    }
#pragma unroll
    for (int r = 0; r < 4; ++r) {
      int row = r0 + rq * 4 + r;
      float ps = acc[r][0] * a_s0 + acc[r][1] * a_s1;
      float pd = acc[r][0] * a_d0 + acc[r][1] * a_d1;
#pragma unroll
      for (int msk = 1; msk < 16; msk <<= 1) {
        ps += __shfl_xor(ps, msk);
        pd += __shfl_xor(pd, msk);
      }
      if (row < N) {
        hbf[(size_t)row * 64 + pr] = pack_bf2(acc[r][0], acc[r][1]);
        if ((pr & 15) == 0) {
          as_out[row * 4 + (pr >> 4)] = ps;
          ad_out[row * 4 + (pr >> 4)] = pd;
        }
      }
    }
  }
}

// ---------------- per-dst softmax+agg+LN+ELU (r8 structure, best measured) ----------------
__global__ __launch_bounds__(256) void k_gat_agg(const int* __restrict__ offs, const int* __restrict__ csr,
                                                 const float* __restrict__ as, const float* __restrict__ ad,
                                                 const uint4* __restrict__ hb, const float* __restrict__ bias,
                                                 const float* __restrict__ gam, const float* __restrict__ bet,
                                                 float* __restrict__ out, int ostride, int N) {
  int wave = threadIdx.x >> 6, lane = threadIdx.x & 63;
  int dst = blockIdx.x * 4 + wave;
  if (dst >= N) return;
  int q = lane & 15, g = lane >> 4, head = q >> 2;
  float ad_h = ad[dst * 4 + head];
  float p_self = __expf(leaky(as[dst * 4 + head] + ad_h));
  float acc[8];
#pragma unroll
  for (int k = 0; k < 8; ++k) acc[k] = 0.f;
  float ssum = 0.f;
  int beg = offs[dst], end = offs[dst + 1];
  for (int base = beg; base < end; base += 64) {
    int idx = base + lane;
    int my = (idx < end) ? csr[idx] : 0;
    int cnt = min(64, end - base);
    int njj = (cnt + 3) >> 2;
    int s0 = __shfl(my, g);
    bool v0 = g < cnt;
    int ss0 = v0 ? s0 : 0;
    float asv0 = as[ss0 * 4 + head];
    uint4 h0 = hb[(size_t)ss0 * 16 + q];
    for (int j = 0; j < njj; ++j) {
      int sel1 = (j + 1) * 4 + g;
      int s1 = __shfl(my, sel1 & 63);
      bool v1 = sel1 < cnt;
      int ss1 = v1 ? s1 : 0;
      float asv1 = as[ss1 * 4 + head];
      uint4 h1 = hb[(size_t)ss1 * 16 + q];
      float p = v0 ? __expf(leaky(asv0 + ad_h)) : 0.f;
      ssum += p;
#pragma unroll
      for (int k = 0; k < 4; ++k) {
        unsigned u = (&h0.x)[k];
        acc[2 * k]     = fmaf(p, __uint_as_float(u << 16), acc[2 * k]);
        acc[2 * k + 1] = fmaf(p, __uint_as_float(u & 0xffff0000u), acc[2 * k + 1]);
      }
      v0 = v1; asv0 = asv1; h0 = h1;
    }
  }
#pragma unroll
  for (int k = 0; k < 8; ++k) {
    acc[k] += __shfl_xor(acc[k], 16);
    acc[k] += __shfl_xor(acc[k], 32);
  }
  float red = ssum;
  red += __shfl_xor(red, 1);
  red += __shfl_xor(red, 2);
  red += __shfl_xor(red, 16);
  red += __shfl_xor(red, 32);
  float denom = 0.25f * red + p_self;
  uint4 hd = hb[(size_t)dst * 16 + q];
#pragma unroll
  for (int k = 0; k < 4; ++k) {
    unsigned u = (&hd.x)[k];
    acc[2 * k]     = fmaf(p_self, __uint_as_float(u << 16), acc[2 * k]);
    acc[2 * k + 1] = fmaf(p_self, __uint_as_float(u & 0xffff0000u), acc[2 * k + 1]);
  }
  int cb = q * 8;
  float inv = 1.f / denom;
  float val[8], part = 0.f;
#pragma unroll
  for (int k = 0; k < 8; ++k) {
    val[k] = acc[k] * inv + bias[cb + k];
    part += val[k];
  }
  part += __shfl_xor(part, 1);
  part += __shfl_xor(part, 2);
  part += __shfl_xor(part, 4);
  part += __shfl_xor(part, 8);
  float mu = part * (1.f / HID);
  float vpart = 0.f;
#pragma unroll
  for (int k = 0; k < 8; ++k) {
    val[k] -= mu;
    vpart += val[k] * val[k];
  }
  vpart += __shfl_xor(vpart, 1);
  vpart += __shfl_xor(vpart, 2);
  vpart += __shfl_xor(vpart, 4);
  vpart += __shfl_xor(vpart, 8);
  float rstd = rsqrtf(vpart * (1.f / HID) + LN_EPS);
  float y[8];
#pragma unroll
  for (int k = 0; k < 8; ++k) {
    float tv = val[k] * rstd * gam[cb + k] + bet[cb + k];
    y[k] = tv > 0.f ? tv : expm1f(tv);
  }
  if (g == 0) {
    *(float4*)&out[(size_t)dst * ostride + cb]     = make_float4(y[0], y[1], y[2], y[3]);
    *(float4*)&out[(size_t)dst * ostride + cb + 4] = make_float4(y[4], y[5], y[6], y[7]);
  }
}

// ---------------- per-graph mean readout (LDS-staged: ~0.5M global atomics total) ----------------
__global__ __launch_bounds__(256) void k_graph_sum(const float* __restrict__ x, int xstride,
                                                   const int* __restrict__ bat,
                                                   float* __restrict__ gsum, float* __restrict__ gcnt, int N) {
  __shared__ float ls[NG * HID];
  __shared__ float lc[NG];
  for (int i = threadIdx.x; i < NG * HID; i += 256) ls[i] = 0.f;
  if (threadIdx.x < NG) lc[threadIdx.x] = 0.f;
  __syncthreads();
  int wave = threadIdx.x >> 6, lane = threadIdx.x & 63;
  for (int n = blockIdx.x * 4 + wave; n < N; n += gridDim.x * 4) {
    int b = bat[n];
    float2 v = *(const float2*)&x[(size_t)n * xstride + lane * 2];
    atomicAdd(&ls[b * HID + lane * 2], v.x);
    atomicAdd(&ls[b * HID + lane * 2 + 1], v.y);
    if (lane == 0) atomicAdd(&lc[b], 1.f);
  }
  __syncthreads();
  for (int i = threadIdx.x; i < NG * HID; i += 256) atomicAdd(&gsum[i], ls[i]);
  if (threadIdx.x < NG) atomicAdd(&gcnt[threadIdx.x], lc[threadIdx.x]);
}

// g-half of output
__global__ __launch_bounds__(256) void k_gout(const int* __restrict__ bat, const float* __restrict__ gsum,
                                              const float* __restrict__ gcnt, float* __restrict__ out, int N) {
  int total = N * 32;
  for (int idx = blockIdx.x * blockDim.x + threadIdx.x; idx < total; idx += gridDim.x * blockDim.x) {
    int n = idx >> 5, qq = idx & 31;
    int b = bat[n];
    float rin = 1.f / fmaxf(gcnt[b], 1.f);
    float4 gv = *(const float4*)&gsum[b * HID + qq * 4];
    *(float4*)&out[(size_t)n * 256 + 128 + qq * 4] =
        make_float4(gv.x * rin, gv.y * rin, gv.z * rin, gv.w * rin);
  }
}

extern "C" void kernel_launch(void* const* d_in, const int* in_sizes, int n_in,
                              void* d_out, int out_size, void* d_ws, size_t ws_size,
                              hipStream_t stream) {
  const float* x   = (const float*)d_in[0];
  const int*   ei  = (const int*)d_in[1];
  const int*   bat = (const int*)d_in[2];
  const float* W1  = (const float*)d_in[3];
  const float* as1 = (const float*)d_in[4];
  const float* ad1 = (const float*)d_in[5];
  const float* b1  = (const float*)d_in[6];
  const float* g1  = (const float*)d_in[7];
  const float* be1 = (const float*)d_in[8];
  const float* W2  = (const float*)d_in[9];
  const float* as2 = (const float*)d_in[10];
  const float* ad2 = (const float*)d_in[11];
  const float* b2  = (const float*)d_in[12];
  const float* g2  = (const float*)d_in[13];
  const float* be2 = (const float*)d_in[14];
  int N = in_sizes[0] / HID;
  int E = in_sizes[1] / 2;

  char* p = (char*)d_ws;
  auto alloc = [&](size_t bytes) {
    void* r = (void*)p;
    p += (bytes + 255) & ~(size_t)255;
    return r;
  };
  int*      deg  = (int*)alloc((size_t)N * 4);   // counting, then reused as absolute cursor
  int*      offs = (int*)alloc((size_t)(N + 1) * 4);
  int       nsb  = (N + 1023) / 1024;
  int*      part = (int*)alloc((size_t)nsb * 4);
  int*      csr  = (int*)alloc((size_t)E * 4);
  unsigned* hbf  = (unsigned*)alloc((size_t)N * 64 * 4);   // bf16x2-packed h
  float*    asb  = (float*)alloc((size_t)N * 4 * 4);
  float*    adb  = (float*)alloc((size_t)N * 4 * 4);
  float*    xb   = (float*)alloc((size_t)N * HID * 4);
  float*    gsum = (float*)alloc((size_t)NG * HID * 4);
  float*    gcnt = (float*)alloc((size_t)NG * 4);

  hipMemsetAsync(deg, 0, (size_t)N * 4, stream);
  hipMemsetAsync(gsum, 0, (size_t)NG * HID * 4, stream);
  hipMemsetAsync(gcnt, 0, (size_t)NG * 4, stream);

  int ntiles = (N + 31) / 32;
  int ggrid = ntiles < 512 ? ntiles : 512;
  int ecgrid = 512;
  int agrid = (N + 3) / 4;
  float* xhalf = (float*)d_out;

  // fused: gemm layer 1 + edge_count (independent work, one dispatch)
  k_gemm_ec<<<ggrid + ecgrid, 512, 0, stream>>>(x, HID, W1, as1, ad1, hbf, asb, adb,
                                                N, ntiles, ggrid, ei, E, deg);
  k_scan_a<<<nsb, 1024, 0, stream>>>(deg, offs, part, N);
  k_scan_b<<<1, 1024, 0, stream>>>(part, nsb);
  k_scan_c<<<(N + 255) / 256, 256, 0, stream>>>(offs, part, deg, N);  // deg becomes cursor
  int fgrid = (E + 255) / 256;
  if (fgrid > 2048) fgrid = 2048;
  k_edge_fill<<<fgrid, 256, 0, stream>>>(ei, E, deg, csr);

  k_gat_agg<<<agrid, 256, 0, stream>>>(offs, csr, asb, adb, (const uint4*)hbf, b1, g1, be1,
                                       xb, HID, N);
  k_gemm_ec<<<ggrid, 512, 0, stream>>>(xb, HID, W2, as2, ad2, hbf, asb, adb,
                                       N, ntiles, ggrid, nullptr, 0, nullptr);
  k_gat_agg<<<agrid, 256, 0, stream>>>(offs, csr, asb, adb, (const uint4*)hbf, b2, g2, be2,
                                       xhalf, 256, N);

  k_graph_sum<<<256, 256, 0, stream>>>(xhalf, 256, bat, gsum, gcnt, N);
  int ogrid = (N * 32 + 255) / 256;
  if (ogrid > 4096) ogrid = 4096;
  k_gout<<<ogrid, 256, 0, stream>>>(bat, gsum, gcnt, (float*)d_out, N);
}